// Round 6
// baseline (286.469 us; speedup 1.0000x reference)
//
#include <hip/hip_runtime.h>
#include <math.h>

// ObjectosphereLoss — single-pass fused kernel.
//   sm = softmax(logits); lsm = log(sm + 1e-10)
//   unknown: jr = -(1/12)*sum(lsm) + 1e-4*||f||^2
//   known:   jr = -lsm[y]          + 1e-4*max(10-||f||,0)^2
//   loss = sum(w[y]*jr)/sum(w[y])
//
// Max-free softmax (|logit| small) + algebraic sums:
//   sum(lsm) = sum(x) - 13*log(S);  lsm[y] = x[y] - log(S)   (eps negligible)
//
// Each wave owns 32 CONTIGUOUS rows. Small inputs (logits/ty/unk/weights)
// staged ONCE per wave; the row loop issues only 2 coalesced float4 feature
// loads. Finalize merged via last-block atomic-counter pattern.
//
// Round-5 post-mortem: __launch_bounds__(256,8) capped VGPRs at 64 ->
// hot-loop scratch spills; nontemporal loads bypassed L2 -> ~1.9 TB/s.
// Both reverted: plain loads, (256,4) = 128-VGPR cap (no spill).

typedef float f32x4 __attribute__((ext_vector_type(4)));

constexpr int   CLS  = 13;
constexpr float INV_KNOWN = 1.0f / 12.0f;
constexpr float LAM  = 1e-4f;
constexpr float XI   = 10.0f;

constexpr int RPW   = 32;            // rows per wave (contiguous)
constexpr int BLOCK = 256;           // 4 waves
constexpr int WPB   = BLOCK / 64;
constexpr size_t COUNTER_OFF = 1u << 20;   // counter at 1 MB into d_ws

__global__ __launch_bounds__(256, 4) void obj_main(
    const float*  __restrict__ logits,
    const int*    __restrict__ true_y,
    const int*    __restrict__ is_unknown,
    const f32x4*  __restrict__ feat,
    const float*  __restrict__ weights,
    double*       __restrict__ partials,   // [2 * gridDim.x]
    unsigned*     __restrict__ counter,    // zeroed by memset node each launch
    float*        __restrict__ out,
    int B)
{
    const int lane = threadIdx.x & 63;
    const int wid  = threadIdx.x >> 6;
    const int gw   = blockIdx.x * WPB + wid;
    const int base_row = gw * RPW;

    __shared__ float s_log[WPB][512];

    // ---- one-time staging of small inputs (per wave) ----
    {
        const size_t lbase = (size_t)base_row * CLS;       // 416 floats needed
        const size_t ltot  = (size_t)B * CLS;
        size_t i0 = lbase + (size_t)lane * 4;
        size_t i1 = i0 + 256;
        f32x4 v0 = (f32x4)0.0f, v1 = (f32x4)0.0f;
        if (i0 + 4 <= ltot) v0 = *reinterpret_cast<const f32x4*>(logits + i0);
        if (i1 + 4 <= ltot) v1 = *reinterpret_cast<const f32x4*>(logits + i1);
        *reinterpret_cast<f32x4*>(&s_log[wid][lane * 4])       = v0;
        *reinterpret_cast<f32x4*>(&s_log[wid][256 + lane * 4]) = v1;
    }
    int r_ld = base_row + (lane & 31); if (r_ld >= B) r_ld = B - 1;
    const int   tyv  = true_y[r_ld];        // lane rl holds row base+rl's label
    const int   unkv = is_unknown[r_ld];
    const float wv   = weights[lane < CLS ? lane : 0];
    __syncthreads();

    // ---- row loop: only VMEM = 2 coalesced float4 loads per row ----
    double num = 0.0, den = 0.0;
    int row = base_row;
    f32x4 a = (f32x4)0.0f, b = (f32x4)0.0f;
    if (row < B) {
        const f32x4* fr = feat + (size_t)row * 128;
        a = fr[lane];
        b = fr[lane + 64];
    }

    for (int rl = 0; rl < RPW && row < B; ++rl) {
        // prefetch next (contiguous) row
        f32x4 na = (f32x4)0.0f, nb = (f32x4)0.0f;
        const int nrow = row + 1;
        if (rl + 1 < RPW && nrow < B) {
            const f32x4* fr = feat + (size_t)nrow * 128;
            na = fr[lane];
            nb = fr[lane + 64];
        }

        float ss = fmaf(a.x, a.x, fmaf(a.y, a.y, fmaf(a.z, a.z, a.w * a.w)))
                 + fmaf(b.x, b.x, fmaf(b.y, b.y, fmaf(b.z, b.z, b.w * b.w)));

        const float x = (lane < CLS) ? s_log[wid][rl * CLS + lane] : 0.0f;
        const float e = (lane < CLS) ? __expf(x) : 0.0f;
        float S = e, sx = x;

        // ss: full 64-lane butterfly (6 steps)
        #pragma unroll
        for (int o = 32; o; o >>= 1) ss += __shfl_xor(ss, o, 64);
        // S, sx: nonzero only on lanes <13 -> 16-lane butterfly (4 steps);
        // group-0 lanes (0..15) end with the full sums, lane 0 is what counts.
        #pragma unroll
        for (int o = 8; o; o >>= 1) {
            S  += __shfl_xor(S,  o, 64);
            sx += __shfl_xor(sx, o, 64);
        }

        const int   ty   = __shfl(tyv,  rl, 64);
        const int   unk  = __shfl(unkv, rl, 64);
        const float w    = __shfl(wv,   ty, 64);
        const float x_ty = __shfl(x,    ty, 64);
        const float logS = __logf(S);
        const float mag  = sqrtf(ss);

        const float jr_u = fmaf(LAM, ss, -INV_KNOWN * (sx - (float)CLS * logS));
        const float dk   = fmaxf(XI - mag, 0.0f);
        const float jr_k = fmaf(LAM, dk * dk, logS - x_ty);
        const float jr   = unk ? jr_u : jr_k;

        num += (double)(w * jr);     // only lane 0's copy is consumed
        den += (double)w;

        row = nrow; a = na; b = nb;
    }

    // ---- block reduce (lane 0 of each wave holds valid sums) ----
    __shared__ double s_n[WPB], s_d[WPB];
    __shared__ unsigned s_last;
    if (lane == 0) { s_n[wid] = num; s_d[wid] = den; }
    __syncthreads();
    if (threadIdx.x == 0) {
        double n = 0.0, d = 0.0;
        for (int i = 0; i < WPB; ++i) { n += s_n[i]; d += s_d[i]; }
        __hip_atomic_store(&partials[blockIdx.x], n,
                           __ATOMIC_RELAXED, __HIP_MEMORY_SCOPE_AGENT);
        __hip_atomic_store(&partials[gridDim.x + blockIdx.x], d,
                           __ATOMIC_RELAXED, __HIP_MEMORY_SCOPE_AGENT);
        __threadfence();
        unsigned old = __hip_atomic_fetch_add(counter, 1u,
                           __ATOMIC_ACQ_REL, __HIP_MEMORY_SCOPE_AGENT);
        s_last = (old == gridDim.x - 1) ? 1u : 0u;
    }
    __syncthreads();

    // ---- last block finalizes ----
    if (s_last) {
        __threadfence();
        double n = 0.0, d = 0.0;
        for (int i = threadIdx.x; i < (int)gridDim.x; i += blockDim.x) {
            n += __hip_atomic_load(&partials[i],
                     __ATOMIC_RELAXED, __HIP_MEMORY_SCOPE_AGENT);
            d += __hip_atomic_load(&partials[gridDim.x + i],
                     __ATOMIC_RELAXED, __HIP_MEMORY_SCOPE_AGENT);
        }
        #pragma unroll
        for (int o = 32; o; o >>= 1) {
            n += __shfl_xor(n, o, 64);
            d += __shfl_xor(d, o, 64);
        }
        double* s_fd = (double*)&s_log[0][0];   // reuse LDS
        if (lane == 0) { s_fd[wid] = n; s_fd[WPB + wid] = d; }
        __syncthreads();
        if (threadIdx.x == 0) {
            double tn = 0.0, td = 0.0;
            for (int i = 0; i < WPB; ++i) { tn += s_fd[i]; td += s_fd[WPB + i]; }
            out[0] = (float)(tn / td);
        }
    }
}

extern "C" void kernel_launch(void* const* d_in, const int* in_sizes, int n_in,
                              void* d_out, int out_size, void* d_ws, size_t ws_size,
                              hipStream_t stream)
{
    const float*  logits     = (const float*)d_in[0];
    const int*    true_y     = (const int*)d_in[1];
    const int*    is_unknown = (const int*)d_in[2];
    const f32x4*  feat       = (const f32x4*)d_in[3];
    const float*  weights    = (const float*)d_in[4];
    float*        out        = (float*)d_out;
    const int B = in_sizes[1];                 // 262144 rows

    const int grid = (B + WPB * RPW - 1) / (WPB * RPW);   // 2048
    double*   partials = (double*)d_ws;                    // 2*grid doubles
    unsigned* counter  = (unsigned*)((char*)d_ws + COUNTER_OFF);

    (void)hipMemsetAsync(counter, 0, sizeof(unsigned), stream);
    obj_main<<<grid, BLOCK, 0, stream>>>(logits, true_y, is_unknown, feat,
                                         weights, partials, counter, out, B);
}

// Round 7
// 262.867 us; speedup vs baseline: 1.0898x; 1.0898x over previous
//
#include <hip/hip_runtime.h>
#include <math.h>

// ObjectosphereLoss — fused single-dispatch kernel.
//   sm = softmax(logits); lsm = log(sm + 1e-10)
//   unknown: jr = -(1/12)*sum(lsm) + 1e-4*||f||^2
//   known:   jr = -lsm[y]          + 1e-4*max(10-||f||,0)^2
//   loss = sum(w[y]*jr)/sum(w[y])
//
// Max-free softmax (|logit| small) + algebraic sums:
//   sum(lsm) = sum(x) - 13*log(S);  lsm[y] = x[y] - log(S)   (eps negligible)
//
// ACCESS PATTERN (round-6 post-mortem): rows are STRIDED per wave
// (row += total_waves) so at any instant all 8192 waves sweep one
// contiguous ~16 MB window of the feature array -> collective DRAM
// sweep, good page locality. Contiguous-rows-per-wave (round 6) made
// 8192 scattered streams and collapsed to 810 GB/s.
//
// Finalize fused via last-block atomic counter (validated round 6).

typedef float f32x4 __attribute__((ext_vector_type(4)));

constexpr int   CLS  = 13;
constexpr float INV_KNOWN = 1.0f / 12.0f;
constexpr float LAM  = 1e-4f;
constexpr float XI   = 10.0f;

constexpr int BLOCK = 256;           // 4 waves
constexpr int WPB   = BLOCK / 64;
constexpr size_t COUNTER_OFF = 1u << 20;   // counter at 1 MB into d_ws

__global__ __launch_bounds__(256) void obj_main(
    const float*  __restrict__ logits,
    const int*    __restrict__ true_y,
    const int*    __restrict__ is_unknown,
    const f32x4*  __restrict__ feat,
    const float*  __restrict__ weights,
    double*       __restrict__ partials,   // [2 * gridDim.x]
    unsigned*     __restrict__ counter,    // zeroed by memset node each launch
    float*        __restrict__ out,
    int B)
{
    const int lane = threadIdx.x & 63;
    const int wid  = threadIdx.x >> 6;
    const int gw   = blockIdx.x * WPB + wid;      // global wave id
    const int tw   = gridDim.x * WPB;             // total waves (stride)

    double num = 0.0, den = 0.0;

    int row = gw;
    f32x4 a = (f32x4)0.0f, b = (f32x4)0.0f;
    float x = 0.0f;
    if (row < B) {
        const f32x4* fr = feat + (size_t)row * 128;
        a = fr[lane];
        b = fr[lane + 64];
        if (lane < CLS) x = logits[(size_t)row * CLS + lane];
    }

    while (row < B) {
        const int nrow = row + tw;
        // ---- prefetch next row (strided sweep) ----
        f32x4 na = (f32x4)0.0f, nb = (f32x4)0.0f;
        float nx = 0.0f;
        if (nrow < B) {
            const f32x4* fr = feat + (size_t)nrow * 128;
            na = fr[lane];
            nb = fr[lane + 64];
            if (lane < CLS) nx = logits[(size_t)nrow * CLS + lane];
        }

        // ---- current row ----
        float ss = fmaf(a.x, a.x, fmaf(a.y, a.y, fmaf(a.z, a.z, a.w * a.w)))
                 + fmaf(b.x, b.x, fmaf(b.y, b.y, fmaf(b.z, b.z, b.w * b.w)));
        const float e = (lane < CLS) ? __expf(x) : 0.0f;   // max-free: |x| small
        float S = e, sx = x;                               // x==0 on lanes >= CLS

        // ss needs all 64 lanes: steps o=32,16 ss-only, then 4 fused steps
        // o=8..1 carrying {ss,S,sx}. Lane 0 ends with full sums (S,sx are
        // nonzero only on lanes <13, all within the lane0 16-lane coset).
        ss += __shfl_xor(ss, 32, 64);
        ss += __shfl_xor(ss, 16, 64);
        #pragma unroll
        for (int o = 8; o; o >>= 1) {
            ss += __shfl_xor(ss, o, 64);
            S  += __shfl_xor(S,  o, 64);
            sx += __shfl_xor(sx, o, 64);
        }

        const int   ty   = true_y[row];        // uniform addr -> 1 request
        const int   unk  = is_unknown[row];
        const float w    = weights[ty];
        const float x_ty = __shfl(x, ty, 64);
        const float logS = __logf(S);
        const float mag  = sqrtf(ss);

        const float jr_u = fmaf(LAM, ss, -INV_KNOWN * (sx - (float)CLS * logS));
        const float dk   = fmaxf(XI - mag, 0.0f);
        const float jr_k = fmaf(LAM, dk * dk, logS - x_ty);
        const float jr   = unk ? jr_u : jr_k;

        num += (double)(w * jr);     // only lane 0's copy is consumed
        den += (double)w;

        row = nrow; a = na; b = nb; x = nx;
    }

    // ---- block reduce (lane 0 of each wave holds valid sums) ----
    __shared__ double s_n[WPB], s_d[WPB];
    __shared__ unsigned s_last;
    if (lane == 0) { s_n[wid] = num; s_d[wid] = den; }
    __syncthreads();
    if (threadIdx.x == 0) {
        double n = 0.0, d = 0.0;
        for (int i = 0; i < WPB; ++i) { n += s_n[i]; d += s_d[i]; }
        __hip_atomic_store(&partials[blockIdx.x], n,
                           __ATOMIC_RELAXED, __HIP_MEMORY_SCOPE_AGENT);
        __hip_atomic_store(&partials[gridDim.x + blockIdx.x], d,
                           __ATOMIC_RELAXED, __HIP_MEMORY_SCOPE_AGENT);
        __threadfence();
        unsigned old = __hip_atomic_fetch_add(counter, 1u,
                           __ATOMIC_ACQ_REL, __HIP_MEMORY_SCOPE_AGENT);
        s_last = (old == gridDim.x - 1) ? 1u : 0u;
    }
    __syncthreads();

    // ---- last block finalizes ----
    if (s_last) {
        __threadfence();
        double n = 0.0, d = 0.0;
        for (int i = threadIdx.x; i < (int)gridDim.x; i += blockDim.x) {
            n += __hip_atomic_load(&partials[i],
                     __ATOMIC_RELAXED, __HIP_MEMORY_SCOPE_AGENT);
            d += __hip_atomic_load(&partials[gridDim.x + i],
                     __ATOMIC_RELAXED, __HIP_MEMORY_SCOPE_AGENT);
        }
        #pragma unroll
        for (int o = 32; o; o >>= 1) {
            n += __shfl_xor(n, o, 64);
            d += __shfl_xor(d, o, 64);
        }
        __shared__ double s_fn[WPB], s_fd[WPB];
        if (lane == 0) { s_fn[wid] = n; s_fd[wid] = d; }
        __syncthreads();
        if (threadIdx.x == 0) {
            double tn = 0.0, td = 0.0;
            for (int i = 0; i < WPB; ++i) { tn += s_fn[i]; td += s_fd[i]; }
            out[0] = (float)(tn / td);
        }
    }
}

extern "C" void kernel_launch(void* const* d_in, const int* in_sizes, int n_in,
                              void* d_out, int out_size, void* d_ws, size_t ws_size,
                              hipStream_t stream)
{
    const float*  logits     = (const float*)d_in[0];
    const int*    true_y     = (const int*)d_in[1];
    const int*    is_unknown = (const int*)d_in[2];
    const f32x4*  feat       = (const f32x4*)d_in[3];
    const float*  weights    = (const float*)d_in[4];
    float*        out        = (float*)d_out;
    const int B = in_sizes[1];                 // 262144 rows

    constexpr int GRID = 2048;                 // 8192 waves, 32 rows each
    double*   partials = (double*)d_ws;        // 2*GRID doubles = 32 KB
    unsigned* counter  = (unsigned*)((char*)d_ws + COUNTER_OFF);

    (void)hipMemsetAsync(counter, 0, sizeof(unsigned), stream);
    obj_main<<<GRID, BLOCK, 0, stream>>>(logits, true_y, is_unknown, feat,
                                         weights, partials, counter, out, B);
}

// Round 8
// 101.714 us; speedup vs baseline: 2.8164x; 2.5844x over previous
//
#include <hip/hip_runtime.h>
#include <math.h>

// ObjectosphereLoss — two-dispatch version (round-2 structure restored).
//   sm = softmax(logits); lsm = log(sm + 1e-10)
//   unknown: jr = -(1/12)*sum(lsm) + 1e-4*||f||^2
//   known:   jr = -lsm[y]          + 1e-4*max(10-||f||,0)^2
//   loss = sum(w[y]*jr)/sum(w[y])
//
// Max-free softmax (|logit| small) + algebraic sums:
//   sum(lsm) = sum(x) - 13*log(S);  lsm[y] = x[y] - log(S)   (eps negligible)
//
// Round-7 post-mortem: the fused last-block finalize (2048 serialized
// agent-scope fetch_adds on ONE address + threadfence) cost ~160 us —
// common factor of rounds 5/6/7 (277/286/263 us) vs round 2 (103 us).
// Access pattern was NOT the issue (strided ~= contiguous when fused).
// -> plain per-block partial stores + separate 1-block finalize kernel.

typedef float f32x4 __attribute__((ext_vector_type(4)));

constexpr int   CLS  = 13;
constexpr float INV_KNOWN = 1.0f / 12.0f;
constexpr float LAM  = 1e-4f;
constexpr float XI   = 10.0f;

constexpr int BLOCK = 256;           // 4 waves
constexpr int WPB   = BLOCK / 64;

__global__ __launch_bounds__(256) void obj_main(
    const float*  __restrict__ logits,
    const int*    __restrict__ true_y,
    const int*    __restrict__ is_unknown,
    const f32x4*  __restrict__ feat,
    const float*  __restrict__ weights,
    double*       __restrict__ partials,   // [2 * gridDim.x]
    int B)
{
    const int lane = threadIdx.x & 63;
    const int wid  = threadIdx.x >> 6;
    const int gw   = blockIdx.x * WPB + wid;      // global wave id
    const int tw   = gridDim.x * WPB;             // total waves (stride)

    double num = 0.0, den = 0.0;

    int row = gw;
    f32x4 a = (f32x4)0.0f, b = (f32x4)0.0f;
    float x = 0.0f;
    if (row < B) {
        const f32x4* fr = feat + (size_t)row * 128;
        a = fr[lane];
        b = fr[lane + 64];
        if (lane < CLS) x = logits[(size_t)row * CLS + lane];
    }

    while (row < B) {
        const int nrow = row + tw;
        // ---- prefetch next row (hides HBM latency under reduce chain) ----
        f32x4 na = (f32x4)0.0f, nb = (f32x4)0.0f;
        float nx = 0.0f;
        if (nrow < B) {
            const f32x4* fr = feat + (size_t)nrow * 128;
            na = fr[lane];
            nb = fr[lane + 64];
            if (lane < CLS) nx = logits[(size_t)nrow * CLS + lane];
        }

        // ---- current row ----
        float ss = fmaf(a.x, a.x, fmaf(a.y, a.y, fmaf(a.z, a.z, a.w * a.w)))
                 + fmaf(b.x, b.x, fmaf(b.y, b.y, fmaf(b.z, b.z, b.w * b.w)));
        const float e = (lane < CLS) ? __expf(x) : 0.0f;   // max-free
        float S = e, sx = x;                               // x==0 on lanes>=CLS

        // ss: o=32,16 ss-only; then o=8..1 fused {ss,S,sx}. Lane 0 ends
        // with full sums (S,sx nonzero only on lanes <13, inside lane0's
        // 16-lane coset).
        ss += __shfl_xor(ss, 32, 64);
        ss += __shfl_xor(ss, 16, 64);
        #pragma unroll
        for (int o = 8; o; o >>= 1) {
            ss += __shfl_xor(ss, o, 64);
            S  += __shfl_xor(S,  o, 64);
            sx += __shfl_xor(sx, o, 64);
        }

        const int   ty   = true_y[row];        // uniform addr -> 1 request
        const int   unk  = is_unknown[row];
        const float w    = weights[ty];
        const float x_ty = __shfl(x, ty, 64);
        const float logS = __logf(S);
        const float mag  = sqrtf(ss);

        const float jr_u = fmaf(LAM, ss, -INV_KNOWN * (sx - (float)CLS * logS));
        const float dk   = fmaxf(XI - mag, 0.0f);
        const float jr_k = fmaf(LAM, dk * dk, logS - x_ty);
        const float jr   = unk ? jr_u : jr_k;

        num += (double)(w * jr);     // only lane 0's copy is consumed
        den += (double)w;

        row = nrow; a = na; b = nb; x = nx;
    }

    __shared__ double s_num[WPB], s_den[WPB];
    if (lane == 0) { s_num[wid] = num; s_den[wid] = den; }
    __syncthreads();
    if (threadIdx.x == 0) {
        double n = 0.0, d = 0.0;
        for (int i = 0; i < WPB; ++i) { n += s_num[i]; d += s_den[i]; }
        partials[blockIdx.x] = n;
        partials[gridDim.x + blockIdx.x] = d;
    }
}

__global__ __launch_bounds__(256) void obj_final(
    const double* __restrict__ partials, int nparts, float* __restrict__ out)
{
    const int lane = threadIdx.x & 63;
    const int wid  = threadIdx.x >> 6;
    double n = 0.0, d = 0.0;
    for (int i = threadIdx.x; i < nparts; i += blockDim.x) {
        n += partials[i];
        d += partials[nparts + i];
    }
    #pragma unroll
    for (int o = 32; o; o >>= 1) {
        n += __shfl_xor(n, o, 64);
        d += __shfl_xor(d, o, 64);
    }
    __shared__ double s_n[4], s_d[4];
    if (lane == 0) { s_n[wid] = n; s_d[wid] = d; }
    __syncthreads();
    if (threadIdx.x == 0) {
        double tn = 0.0, td = 0.0;
        for (int i = 0; i < 4; ++i) { tn += s_n[i]; td += s_d[i]; }
        out[0] = (float)(tn / td);
    }
}

extern "C" void kernel_launch(void* const* d_in, const int* in_sizes, int n_in,
                              void* d_out, int out_size, void* d_ws, size_t ws_size,
                              hipStream_t stream)
{
    const float*  logits     = (const float*)d_in[0];
    const int*    true_y     = (const int*)d_in[1];
    const int*    is_unknown = (const int*)d_in[2];
    const f32x4*  feat       = (const f32x4*)d_in[3];
    const float*  weights    = (const float*)d_in[4];
    float*        out        = (float*)d_out;
    const int B = in_sizes[1];          // 262144 rows

    double* partials = (double*)d_ws;   // 2 * GRID doubles = 32 KB
    constexpr int GRID = 2048;          // 8192 waves, 32 rows each

    obj_main<<<GRID, BLOCK, 0, stream>>>(logits, true_y, is_unknown, feat,
                                         weights, partials, B);
    obj_final<<<1, 256, 0, stream>>>(partials, GRID, out);
}

// Round 9
// 101.701 us; speedup vs baseline: 2.8168x; 1.0001x over previous
//
#include <hip/hip_runtime.h>
#include <math.h>

// ObjectosphereLoss — two-dispatch, DPP-reduced.
//   sm = softmax(logits); lsm = log(sm + 1e-10)
//   unknown: jr = -(1/12)*sum(lsm) + 1e-4*||f||^2
//   known:   jr = -lsm[y]          + 1e-4*max(10-||f||,0)^2
//   loss = sum(w[y]*jr)/sum(w[y])
//
// Max-free softmax (|logit| small) + algebraic sums:
//   sum(lsm) = sum(x) - 13*log(S);  lsm[y] = x[y] - log(S)   (eps negligible)
//
// Round-8 -> 9: replace the 14 ds_swizzle shuffle ops/row (DS pipe, ~25cy
// each, ~350cy serial chain) with DPP adds in the VALU pipe (~4cy each):
//   ss  : 4x row_shr + row_bcast15(mask A) + row_bcast31(mask C) -> lane 63
//   S,sx: nonzero only lanes 0..12 (inside row 0) -> 4x row_shr -> lane 15
// readlane pulls the sums; x[ty] via readlane(x, ty) (ty wave-uniform).
// Zero DS ops in the hot loop.

typedef float f32x4 __attribute__((ext_vector_type(4)));

constexpr int   CLS  = 13;
constexpr float INV_KNOWN = 1.0f / 12.0f;
constexpr float LAM  = 1e-4f;
constexpr float XI   = 10.0f;

constexpr int BLOCK = 256;           // 4 waves
constexpr int WPB   = BLOCK / 64;

template<int CTRL, int RMASK>
__device__ __forceinline__ float dpp_add(float v) {
    int t = __builtin_amdgcn_update_dpp(0, __builtin_bit_cast(int, v),
                                        CTRL, RMASK, 0xF, true);
    return v + __builtin_bit_cast(float, t);
}
__device__ __forceinline__ float read_lane_f(float v, int lane) {
    return __builtin_bit_cast(float,
        __builtin_amdgcn_readlane(__builtin_bit_cast(int, v), lane));
}

__global__ __launch_bounds__(256) void obj_main(
    const float*  __restrict__ logits,
    const int*    __restrict__ true_y,
    const int*    __restrict__ is_unknown,
    const f32x4*  __restrict__ feat,
    const float*  __restrict__ weights,
    double*       __restrict__ partials,   // [2 * gridDim.x]
    int B)
{
    const int lane = threadIdx.x & 63;
    const int wid  = threadIdx.x >> 6;
    const int gw   = blockIdx.x * WPB + wid;      // global wave id
    const int tw   = gridDim.x * WPB;             // total waves (stride)

    double num = 0.0, den = 0.0;

    int row = gw;
    f32x4 a = (f32x4)0.0f, b = (f32x4)0.0f;
    float x = 0.0f;
    if (row < B) {
        const f32x4* fr = feat + (size_t)row * 128;
        a = fr[lane];
        b = fr[lane + 64];
        if (lane < CLS) x = logits[(size_t)row * CLS + lane];
    }

    while (row < B) {
        const int nrow = row + tw;
        // ---- prefetch next row (hides HBM latency under compute) ----
        f32x4 na = (f32x4)0.0f, nb = (f32x4)0.0f;
        float nx = 0.0f;
        if (nrow < B) {
            const f32x4* fr = feat + (size_t)nrow * 128;
            na = fr[lane];
            nb = fr[lane + 64];
            if (lane < CLS) nx = logits[(size_t)nrow * CLS + lane];
        }

        // ---- current row ----
        float ss = fmaf(a.x, a.x, fmaf(a.y, a.y, fmaf(a.z, a.z, a.w * a.w)))
                 + fmaf(b.x, b.x, fmaf(b.y, b.y, fmaf(b.z, b.z, b.w * b.w)));
        const float e = (lane < CLS) ? __expf(x) : 0.0f;   // max-free
        float S = e, sx = x;                               // x==0 on lanes>=CLS

        // DPP reductions (VALU pipe, no LDS):
        ss = dpp_add<0x111, 0xF>(ss);       // row_shr:1
        S  = dpp_add<0x111, 0xF>(S);
        sx = dpp_add<0x111, 0xF>(sx);
        ss = dpp_add<0x112, 0xF>(ss);       // row_shr:2
        S  = dpp_add<0x112, 0xF>(S);
        sx = dpp_add<0x112, 0xF>(sx);
        ss = dpp_add<0x114, 0xF>(ss);       // row_shr:4
        S  = dpp_add<0x114, 0xF>(S);
        sx = dpp_add<0x114, 0xF>(sx);
        ss = dpp_add<0x118, 0xF>(ss);       // row_shr:8
        S  = dpp_add<0x118, 0xF>(S);
        sx = dpp_add<0x118, 0xF>(sx);
        ss = dpp_add<0x142, 0xA>(ss);       // row_bcast15 -> rows 1,3
        ss = dpp_add<0x143, 0xC>(ss);       // row_bcast31 -> rows 2,3

        const int   ty    = true_y[row];       // wave-uniform
        const int   unk   = is_unknown[row];
        const float w     = weights[ty];
        const float ss_t  = read_lane_f(ss, 63);
        const float S_t   = read_lane_f(S,  15);
        const float sx_t  = read_lane_f(sx, 15);
        const float x_ty  = read_lane_f(x,  ty);
        const float logS  = __logf(S_t);
        const float mag   = sqrtf(ss_t);

        const float jr_u = fmaf(LAM, ss_t, -INV_KNOWN * (sx_t - (float)CLS * logS));
        const float dk   = fmaxf(XI - mag, 0.0f);
        const float jr_k = fmaf(LAM, dk * dk, logS - x_ty);
        const float jr   = unk ? jr_u : jr_k;

        num += (double)(w * jr);     // uniform across lanes; lane 0 consumed
        den += (double)w;

        row = nrow; a = na; b = nb; x = nx;
    }

    __shared__ double s_num[WPB], s_den[WPB];
    if (lane == 0) { s_num[wid] = num; s_den[wid] = den; }
    __syncthreads();
    if (threadIdx.x == 0) {
        double n = 0.0, d = 0.0;
        for (int i = 0; i < WPB; ++i) { n += s_num[i]; d += s_den[i]; }
        partials[blockIdx.x] = n;
        partials[gridDim.x + blockIdx.x] = d;
    }
}

__global__ __launch_bounds__(256) void obj_final(
    const double* __restrict__ partials, int nparts, float* __restrict__ out)
{
    const int lane = threadIdx.x & 63;
    const int wid  = threadIdx.x >> 6;
    double n = 0.0, d = 0.0;
    for (int i = threadIdx.x; i < nparts; i += blockDim.x) {
        n += partials[i];
        d += partials[nparts + i];
    }
    #pragma unroll
    for (int o = 32; o; o >>= 1) {
        n += __shfl_xor(n, o, 64);
        d += __shfl_xor(d, o, 64);
    }
    __shared__ double s_n[4], s_d[4];
    if (lane == 0) { s_n[wid] = n; s_d[wid] = d; }
    __syncthreads();
    if (threadIdx.x == 0) {
        double tn = 0.0, td = 0.0;
        for (int i = 0; i < 4; ++i) { tn += s_n[i]; td += s_d[i]; }
        out[0] = (float)(tn / td);
    }
}

extern "C" void kernel_launch(void* const* d_in, const int* in_sizes, int n_in,
                              void* d_out, int out_size, void* d_ws, size_t ws_size,
                              hipStream_t stream)
{
    const float*  logits     = (const float*)d_in[0];
    const int*    true_y     = (const int*)d_in[1];
    const int*    is_unknown = (const int*)d_in[2];
    const f32x4*  feat       = (const f32x4*)d_in[3];
    const float*  weights    = (const float*)d_in[4];
    float*        out        = (float*)d_out;
    const int B = in_sizes[1];          // 262144 rows

    double* partials = (double*)d_ws;   // 2 * GRID doubles = 32 KB
    constexpr int GRID = 2048;          // 8192 waves, 32 rows each

    obj_main<<<GRID, BLOCK, 0, stream>>>(logits, true_y, is_unknown, feat,
                                         weights, partials, B);
    obj_final<<<1, 256, 0, stream>>>(partials, GRID, out);
}